// Round 2
// baseline (246.626 us; speedup 1.0000x reference)
//
#include <hip/hip_runtime.h>
#include <hip/hip_bf16.h>

#define IN_DIM 512
#define OUT_DIM 512

typedef unsigned short u16;
typedef __attribute__((ext_vector_type(4))) float f32x4;
typedef __attribute__((ext_vector_type(8))) __bf16 bf16x8;

__device__ __forceinline__ float softplus_f(float r) {
    return (r > 15.0f) ? r : log1pf(expf(r));
}

// ---------------------------------------------------------------------------
// Kernel 1: fold w = w_mu + softplus(w_rho)*w_eps -> bf16 [OUT][IN] (K-major),
//           b = b_mu + softplus(b_rho)*b_eps -> f32 [OUT], into workspace.
// ---------------------------------------------------------------------------
__global__ void prep_kernel(const float* __restrict__ wmu, const float* __restrict__ wrho,
                            const float* __restrict__ weps, const float* __restrict__ bmu,
                            const float* __restrict__ brho, const float* __restrict__ beps,
                            u16* __restrict__ wbf, float* __restrict__ bias) {
    int gid = blockIdx.x * 256 + threadIdx.x;
    int i4 = gid * 4;
    const float4 mu  = *(const float4*)(wmu + i4);
    const float4 rho = *(const float4*)(wrho + i4);
    const float4 ep  = *(const float4*)(weps + i4);
    union { __bf16 h[4]; uint2 u; } pk;
    pk.h[0] = (__bf16)(mu.x + softplus_f(rho.x) * ep.x);
    pk.h[1] = (__bf16)(mu.y + softplus_f(rho.y) * ep.y);
    pk.h[2] = (__bf16)(mu.z + softplus_f(rho.z) * ep.z);
    pk.h[3] = (__bf16)(mu.w + softplus_f(rho.w) * ep.w);
    *(uint2*)(wbf + i4) = pk.u;
    if (gid < OUT_DIM) {
        bias[gid] = bmu[gid] + softplus_f(brho[gid]) * beps[gid];
    }
}

// ---------------------------------------------------------------------------
// Kernel 2: y = x @ w^T + b, fused dropout. Barrier-free / LDS-free.
//
// Grid: 2048 blocks x 256 thr (4 waves). Block = 128x128 tile, wave = 64x64.
// Each wave independent: x fragments loaded f32 from global (cvt->bf16 in
// regs), w fragments bf16 from L2-resident folded weights. Full K unroll ->
// straight-line code the compiler can pipeline; no syncthreads anywhere.
//
// MFMA operand swap: A=w-frag (out-col = lane&15-of-frag... reg index), B=x-frag.
// D layout: out_row = row0 + r*16 + (lane&15), out_col = col0 + c*16 + lk*4 + reg
// -> lane's 4 acc regs are 4 consecutive out columns => dwordx4 epilogue.
// ---------------------------------------------------------------------------
__global__ __launch_bounds__(256, 3) void bayes_gemm_kernel(
    const float* __restrict__ x, const float* __restrict__ du,
    const u16* __restrict__ wbf, const float* __restrict__ bias,
    float* __restrict__ out)
{
    // XCD-aware swizzle: HW round-robins raw%8 across XCDs; make each XCD's
    // slots a contiguous logical range so col-siblings of one row band share
    // the x band in that XCD's L2.
    const int raw   = blockIdx.x;
    const int lid   = (raw & 7) * 256 + (raw >> 3);
    const int mband = lid >> 2;      // 0..511 : 128-row band
    const int nband = lid & 3;       // 0..3   : 128-col band

    const int tid  = threadIdx.x;
    const int lane = tid & 63;
    const int wv   = tid >> 6;       // wave 0..3
    const int wm   = wv >> 1;        // 0..1
    const int wn   = wv & 1;         // 0..1
    const int l15  = lane & 15;
    const int lk   = lane >> 4;      // 0..3

    const int row0 = mband * 128 + wm * 64;   // wave's 64 output rows
    const int col0 = nband * 128 + wn * 64;   // wave's 64 output cols

    // Per-lane base pointers; K-step offsets become immediate offsets.
    const float* px0 = x + (size_t)(row0 +  0 + l15) * IN_DIM + lk * 8;
    const float* px1 = x + (size_t)(row0 + 16 + l15) * IN_DIM + lk * 8;
    const float* px2 = x + (size_t)(row0 + 32 + l15) * IN_DIM + lk * 8;
    const float* px3 = x + (size_t)(row0 + 48 + l15) * IN_DIM + lk * 8;
    const u16*   pw0 = wbf + (col0 +  0 + l15) * IN_DIM + lk * 8;
    const u16*   pw1 = wbf + (col0 + 16 + l15) * IN_DIM + lk * 8;
    const u16*   pw2 = wbf + (col0 + 32 + l15) * IN_DIM + lk * 8;
    const u16*   pw3 = wbf + (col0 + 48 + l15) * IN_DIM + lk * 8;

    f32x4 acc[4][4] = {};   // [c][r]

#pragma unroll
    for (int ks = 0; ks < 16; ++ks) {
        const int ko = ks * 32;   // k offset in elements

        bf16x8 wf[4];
        wf[0] = *(const bf16x8*)(pw0 + ko);
        wf[1] = *(const bf16x8*)(pw1 + ko);
        wf[2] = *(const bf16x8*)(pw2 + ko);
        wf[3] = *(const bf16x8*)(pw3 + ko);

        float4 xa[4][2];
        xa[0][0] = *(const float4*)(px0 + ko); xa[0][1] = *(const float4*)(px0 + ko + 4);
        xa[1][0] = *(const float4*)(px1 + ko); xa[1][1] = *(const float4*)(px1 + ko + 4);
        xa[2][0] = *(const float4*)(px2 + ko); xa[2][1] = *(const float4*)(px2 + ko + 4);
        xa[3][0] = *(const float4*)(px3 + ko); xa[3][1] = *(const float4*)(px3 + ko + 4);

        bf16x8 xf[4];
#pragma unroll
        for (int r = 0; r < 4; ++r) {
            bf16x8 v;
            v[0] = (__bf16)xa[r][0].x; v[1] = (__bf16)xa[r][0].y;
            v[2] = (__bf16)xa[r][0].z; v[3] = (__bf16)xa[r][0].w;
            v[4] = (__bf16)xa[r][1].x; v[5] = (__bf16)xa[r][1].y;
            v[6] = (__bf16)xa[r][1].z; v[7] = (__bf16)xa[r][1].w;
            xf[r] = v;
        }

#pragma unroll
        for (int c = 0; c < 4; ++c)
#pragma unroll
            for (int r = 0; r < 4; ++r)
                acc[c][r] = __builtin_amdgcn_mfma_f32_16x16x32_bf16(
                    wf[c], xf[r], acc[c][r], 0, 0, 0);
    }

    // ---- epilogue: bias + inverted dropout, fully vectorized dwordx4
#pragma unroll
    for (int c = 0; c < 4; ++c) {
        const float4 b4 = *(const float4*)(bias + col0 + c * 16 + lk * 4);
#pragma unroll
        for (int r = 0; r < 4; ++r) {
            size_t off = (size_t)(row0 + r * 16 + l15) * OUT_DIM + col0 + c * 16 + lk * 4;
            const float4 u4 = *(const float4*)(du + off);
            float4 o;
            o.x = (acc[c][r][0] + b4.x) * ((u4.x >= 0.2f) ? 1.25f : 0.0f);
            o.y = (acc[c][r][1] + b4.y) * ((u4.y >= 0.2f) ? 1.25f : 0.0f);
            o.z = (acc[c][r][2] + b4.z) * ((u4.z >= 0.2f) ? 1.25f : 0.0f);
            o.w = (acc[c][r][3] + b4.w) * ((u4.w >= 0.2f) ? 1.25f : 0.0f);
            *(float4*)(out + off) = o;
        }
    }
}

extern "C" void kernel_launch(void* const* d_in, const int* in_sizes, int n_in,
                              void* d_out, int out_size, void* d_ws, size_t ws_size,
                              hipStream_t stream) {
    const float* x    = (const float*)d_in[0];
    const float* wmu  = (const float*)d_in[1];
    const float* wrho = (const float*)d_in[2];
    const float* bmu  = (const float*)d_in[3];
    const float* brho = (const float*)d_in[4];
    const float* weps = (const float*)d_in[5];
    const float* beps = (const float*)d_in[6];
    const float* du   = (const float*)d_in[7];
    float* out = (float*)d_out;

    u16*   wbf  = (u16*)d_ws;
    float* bias = (float*)((char*)d_ws + OUT_DIM * IN_DIM * sizeof(u16));

    prep_kernel<<<256, 256, 0, stream>>>(wmu, wrho, weps, bmu, brho, beps, wbf, bias);
    bayes_gemm_kernel<<<2048, 256, 0, stream>>>(x, du, wbf, bias, out);
}

// Round 3
// 189.120 us; speedup vs baseline: 1.3041x; 1.3041x over previous
//
#include <hip/hip_runtime.h>
#include <hip/hip_bf16.h>

#define IN_DIM 512
#define OUT_DIM 512

typedef unsigned short u16;
typedef __attribute__((ext_vector_type(4))) float f32x4;
typedef __attribute__((ext_vector_type(8))) __bf16 bf16x8;

__device__ __forceinline__ float softplus_f(float r) {
    return (r > 15.0f) ? r : log1pf(expf(r));
}

// ---------------------------------------------------------------------------
// Kernel 1: fold w = w_mu + softplus(w_rho)*w_eps -> bf16 [OUT][IN] (K-major),
//           b = b_mu + softplus(b_rho)*b_eps -> f32 [OUT], into workspace.
// ---------------------------------------------------------------------------
__global__ void prep_kernel(const float* __restrict__ wmu, const float* __restrict__ wrho,
                            const float* __restrict__ weps, const float* __restrict__ bmu,
                            const float* __restrict__ brho, const float* __restrict__ beps,
                            u16* __restrict__ wbf, float* __restrict__ bias) {
    int gid = blockIdx.x * 256 + threadIdx.x;
    int i4 = gid * 4;
    const float4 mu  = *(const float4*)(wmu + i4);
    const float4 rho = *(const float4*)(wrho + i4);
    const float4 ep  = *(const float4*)(weps + i4);
    union { __bf16 h[4]; uint2 u; } pk;
    pk.h[0] = (__bf16)(mu.x + softplus_f(rho.x) * ep.x);
    pk.h[1] = (__bf16)(mu.y + softplus_f(rho.y) * ep.y);
    pk.h[2] = (__bf16)(mu.z + softplus_f(rho.z) * ep.z);
    pk.h[3] = (__bf16)(mu.w + softplus_f(rho.w) * ep.w);
    *(uint2*)(wbf + i4) = pk.u;
    if (gid < OUT_DIM) {
        bias[gid] = bmu[gid] + softplus_f(brho[gid]) * beps[gid];
    }
}

// ---------------------------------------------------------------------------
// Kernel 2: y = x @ w^T + b, fused dropout.
// Grid: 4096 blocks (1024 M-bands x 4 N-bands), 256 thr = 4 waves (2M x 2N).
// Block tile 64x128, wave tile 32x64, BK=64, 8 K-tiles.
// Depth-2 software pipeline: x loads for tile t+2 issued before compute(t);
// cvt+LDS-write of tile t+1 after compute(t) -> compiler's auto-wait there is
// a COUNTED vmcnt (t+2's loads stay in flight across the barrier).
// A=w (from L2-resident folded weights), B=x (from swizzled LDS);
// D-layout: row=l15, col=lk*4+reg -> dwordx4 du/out epilogue.
// ---------------------------------------------------------------------------
__global__ __launch_bounds__(256, 4) void bayes_gemm_kernel(
    const float* __restrict__ x, const float* __restrict__ du,
    const u16* __restrict__ wbf, const float* __restrict__ bias,
    float* __restrict__ out)
{
    __shared__ u16 ldsA[2][64 * 64];   // 2 x 8 KB bf16 x-tiles

    const int raw   = blockIdx.x;
    const int lid   = (raw & 7) * 512 + (raw >> 3);   // bijective, 4096 % 8 == 0
    const int mband = lid >> 2;      // 0..1023 : 64-row band
    const int nband = lid & 3;       // 0..3    : 128-col band

    const int tid  = threadIdx.x;
    const int lane = tid & 63;
    const int wv   = tid >> 6;
    const int wm   = wv >> 1;        // 0..1
    const int wn   = wv & 1;         // 0..1
    const int l15  = lane & 15;
    const int lk   = lane >> 4;      // 0..3

    const int row0 = mband * 64;
    const int wrow = wm * 32;
    const int col0 = nband * 128 + wn * 64;

    // staging: thread covers row srow, 4 float4 chunks (16 f32) of the 64-wide k-slab
    const int srow = tid >> 2;          // 0..63
    const int sc4  = (tid & 3) * 4;     // 0,4,8,12 ; chunk i at sc4 + i*16
    const float* xp = x + (size_t)(row0 + srow) * IN_DIM + sc4;

    const u16* pw0 = wbf + (col0 +  0 + l15) * IN_DIM + lk * 8;
    const u16* pw1 = wbf + (col0 + 16 + l15) * IN_DIM + lk * 8;
    const u16* pw2 = wbf + (col0 + 32 + l15) * IN_DIM + lk * 8;
    const u16* pw3 = wbf + (col0 + 48 + l15) * IN_DIM + lk * 8;

    float4 sreg[2][4];
    f32x4 acc[2][4] = {};   // [m][n]

    // helper lambdas (inlined; all indices compile-time after unroll)
    auto issue_loads = [&](int tile, int buf) {
#pragma unroll
        for (int i = 0; i < 4; ++i)
            sreg[buf][i] = *(const float4*)(xp + tile * 64 + i * 16);
    };
    auto write_tile = [&](int buf) {
#pragma unroll
        for (int i = 0; i < 4; ++i) {
            int k0 = sc4 + i * 16;
            union { __bf16 h[4]; uint2 u; } pk;
            pk.h[0] = (__bf16)sreg[buf][i].x;
            pk.h[1] = (__bf16)sreg[buf][i].y;
            pk.h[2] = (__bf16)sreg[buf][i].z;
            pk.h[3] = (__bf16)sreg[buf][i].w;
            int off = srow * 64 + (k0 ^ ((srow & 7) << 3));
            *(uint2*)&ldsA[buf][off] = pk.u;
        }
    };

    // ---- prologue: tiles 0 and 1 in flight; tile 0 staged
    issue_loads(0, 0);
    issue_loads(1, 1);
    write_tile(0);            // compiler waits only tile0's loads (vmcnt(4))
    __syncthreads();

#pragma unroll
    for (int t = 0; t < 8; ++t) {
        if (t + 2 < 8) issue_loads(t + 2, t & 1);   // sreg[t&1] was consumed at iter t-1

        // ---- compute tile t from ldsA[t&1]
#pragma unroll
        for (int kk = 0; kk < 2; ++kk) {
            bf16x8 wf[4];
            wf[0] = *(const bf16x8*)(pw0 + t * 64 + kk * 32);
            wf[1] = *(const bf16x8*)(pw1 + t * 64 + kk * 32);
            wf[2] = *(const bf16x8*)(pw2 + t * 64 + kk * 32);
            wf[3] = *(const bf16x8*)(pw3 + t * 64 + kk * 32);
            bf16x8 xf[2];
#pragma unroll
            for (int m = 0; m < 2; ++m) {
                int row = wrow + m * 16 + l15;
                int off = row * 64 + ((kk * 32 + lk * 8) ^ ((row & 7) << 3));
                xf[m] = *(const bf16x8*)&ldsA[t & 1][off];
            }
#pragma unroll
            for (int m = 0; m < 2; ++m)
#pragma unroll
                for (int n = 0; n < 4; ++n)
                    acc[m][n] = __builtin_amdgcn_mfma_f32_16x16x32_bf16(
                        (n == 0) ? wf[0] : (n == 1) ? wf[1] : (n == 2) ? wf[2] : wf[3],
                        xf[m], acc[m][n], 0, 0, 0);
        }

        if (t + 1 < 8) {
            write_tile((t + 1) & 1);   // auto-wait = counted vmcnt (t+2 still in flight)
            __syncthreads();
        }
    }

    // ---- epilogue: bias + inverted dropout, dwordx4 throughout
#pragma unroll
    for (int m = 0; m < 2; ++m) {
#pragma unroll
        for (int n = 0; n < 4; ++n) {
            const float4 b4 = *(const float4*)(bias + col0 + n * 16 + lk * 4);
            size_t off = (size_t)(row0 + wrow + m * 16 + l15) * OUT_DIM
                       + col0 + n * 16 + lk * 4;
            const float4 u4 = *(const float4*)(du + off);
            float4 o;
            o.x = (acc[m][n][0] + b4.x) * ((u4.x >= 0.2f) ? 1.25f : 0.0f);
            o.y = (acc[m][n][1] + b4.y) * ((u4.y >= 0.2f) ? 1.25f : 0.0f);
            o.z = (acc[m][n][2] + b4.z) * ((u4.z >= 0.2f) ? 1.25f : 0.0f);
            o.w = (acc[m][n][3] + b4.w) * ((u4.w >= 0.2f) ? 1.25f : 0.0f);
            *(float4*)(out + off) = o;
        }
    }
}

extern "C" void kernel_launch(void* const* d_in, const int* in_sizes, int n_in,
                              void* d_out, int out_size, void* d_ws, size_t ws_size,
                              hipStream_t stream) {
    const float* x    = (const float*)d_in[0];
    const float* wmu  = (const float*)d_in[1];
    const float* wrho = (const float*)d_in[2];
    const float* bmu  = (const float*)d_in[3];
    const float* brho = (const float*)d_in[4];
    const float* weps = (const float*)d_in[5];
    const float* beps = (const float*)d_in[6];
    const float* du   = (const float*)d_in[7];
    float* out = (float*)d_out;

    u16*   wbf  = (u16*)d_ws;
    float* bias = (float*)((char*)d_ws + OUT_DIM * IN_DIM * sizeof(u16));

    prep_kernel<<<256, 256, 0, stream>>>(wmu, wrho, weps, bmu, brho, beps, wbf, bias);
    bayes_gemm_kernel<<<4096, 256, 0, stream>>>(x, du, wbf, bias, out);
}